// Round 6
// baseline (119.246 us; speedup 1.0000x reference)
//
#include <hip/hip_runtime.h>
#include <math.h>

#define OUT 260
#define TAPS 6
#define IMG_H 2048
#define IMG_W 2048
#define ROW_F (IMG_W * 3)            // 6144 floats per image row
#define NB 10
#define TH 0.8f
#define SEGS 9                       // 8 segs of 32 cols + 1 seg of 4
#define QB 32
#define LROW 800                     // floats per combined LDS row (worst span ~784)
#define MAXM 14                      // max rows in a p-pair union (Δ<=8 since scale<=7.88)

__device__ __forceinline__ float sincf(float x) {
    if (x == 0.0f) return 1.0f;
    float px = 3.14159265358979323846f * x;
    return __sinf(px) / px;
}

// Record layout per (box, idx), 16 dwords = 64 B:
//   f[0..5]  : normalized weights (vertical table: also * vmask)
//   i[8..13] : horizontal: clamped absolute float index (x0+t)*3
//              vertical:   clamped absolute row index (t+y0)
//   i[14]    : vertical: unclamped tap base (floor(src)-2); horizontal: 0
//   i[15]    : pad

__global__ __launch_bounds__(320) void tables_kernel(
    const float* __restrict__ scores, const float* __restrict__ boxes,
    float* __restrict__ htab, float* __restrict__ vtab)
{
    const int box = blockIdx.x;
    const float b0 = boxes[box * 4 + 0];
    const float b1 = boxes[box * 4 + 1];
    const float b2 = boxes[box * 4 + 2];
    const float b3 = boxes[box * 4 + 3];

    const int y0 = (int)(b0 * (float)IMG_H);
    const int x0 = (int)(b1 * (float)IMG_W);
    const int y1 = (int)(b2 * (float)IMG_H);
    const int x1 = (int)(b3 * (float)IMG_W);
    const int ch = max(y1 - y0, 1);
    const int cw = max(x1 - x0, 1);

    const bool valid = (scores[0] >= TH) && (scores[box] >= TH)
                    && (b1 >= 0.0f) && (b3 <= 1.0f);
    const float vmask = valid ? 1.0f : 0.0f;

    const int t = threadIdx.x;
    if (t >= OUT) return;

    // ---- horizontal record ----
    {
        const float src = ((float)t + 0.5f) * ((float)cw / (float)OUT) - 0.5f;
        const int base = (int)floorf(src) - 2;
        float w[TAPS]; int id[TAPS];
        float s = 0.0f;
        #pragma unroll
        for (int k = 0; k < TAPS; ++k) {
            const float d = src - (float)(base + k);
            const float wv = (fabsf(d) < 3.0f) ? sincf(d) * sincf(d * (1.0f / 3.0f)) : 0.0f;
            w[k] = wv; s += wv;
            int tt = base + k; tt = tt < 0 ? 0 : tt; tt = tt > cw - 1 ? cw - 1 : tt;
            id[k] = (x0 + tt) * 3;
        }
        const float inv = 1.0f / s;
        float* h = htab + ((size_t)(box * OUT + t) << 4);
        int*   hi = (int*)h;
        #pragma unroll
        for (int k = 0; k < TAPS; ++k) { h[k] = w[k] * inv; hi[8 + k] = id[k]; }
        h[6] = 0.0f; h[7] = 0.0f; hi[14] = 0; hi[15] = 0;
    }

    // ---- vertical record (vmask folded in, unclamped base stored) ----
    {
        const float src = ((float)t + 0.5f) * ((float)ch / (float)OUT) - 0.5f;
        const int base = (int)floorf(src) - 2;
        float w[TAPS]; int id[TAPS];
        float s = 0.0f;
        #pragma unroll
        for (int k = 0; k < TAPS; ++k) {
            const float d = src - (float)(base + k);
            const float wv = (fabsf(d) < 3.0f) ? sincf(d) * sincf(d * (1.0f / 3.0f)) : 0.0f;
            w[k] = wv; s += wv;
            int tt = base + k; tt = tt < 0 ? 0 : tt; tt = tt > ch - 1 ? ch - 1 : tt;
            id[k] = tt + y0;
        }
        const float inv = vmask / s;
        float* v = vtab + ((size_t)(box * OUT + t) << 4);
        int*   vi = (int*)v;
        #pragma unroll
        for (int k = 0; k < TAPS; ++k) { v[k] = w[k] * inv; vi[8 + k] = id[k]; }
        v[6] = 0.0f; v[7] = 0.0f; vi[14] = base; vi[15] = 0;
    }
}

// Each block: one (box, p-pair, 32-col segment). Stage the consecutive
// row-union of both p's 6-tap windows once; produce TWO combined LDS rows;
// lanes 0..31 compute p0, lanes 32..63 compute p1.
__global__ __launch_bounds__(64) void crop_resize_pair(
    const float* __restrict__ img,
    const float* __restrict__ htab,
    const float* __restrict__ vtab,
    float* __restrict__ out)
{
    const int seg = blockIdx.x;      // 0..8
    const int py  = blockIdx.y;      // 0..129 -> p0 = 2*py
    const int box = blockIdx.z;      // 0..9
    const int q0  = seg * QB;
    const int qcount = min(QB, OUT - q0);   // 32 or 4
    const int p0 = 2 * py;

    // ---- vertical records for p0, p1 ----
    const float* v0 = vtab + ((size_t)(box * OUT + p0) << 4);
    const float* v1 = vtab + ((size_t)(box * OUT + p0 + 1) << 4);
    const int* vi0 = (const int*)v0;
    const int* vi1 = (const int*)v1;

    int dlt = vi1[14] - vi0[14];     // 0..8
    dlt = dlt < 0 ? 0 : (dlt > MAXM - TAPS ? MAXM - TAPS : dlt);
    const int m = dlt + TAPS;        // rows in union, 6..14

    float wa[MAXM], wb[MAXM];
    int   rowi[MAXM];
    #pragma unroll
    for (int j = 0; j < MAXM; ++j) {
        const float wA = (j < TAPS) ? v0[j] : 0.0f;
        const int jb = j - dlt;
        const float wB = (jb >= 0 && jb < TAPS) ? v1[jb] : 0.0f;
        wa[j] = wA; wb[j] = wB;
        rowi[j] = (j < TAPS) ? vi0[8 + j] : vi1[8 + ((jb < 0) ? 0 : (jb > 5 ? 5 : jb))];
    }

    // ---- staged span from first/last q's horizontal tap indices ----
    const int* hi_first = (const int*)(htab + ((size_t)(box * OUT + q0) << 4));
    const int* hi_last  = (const int*)(htab + ((size_t)(box * OUT + q0 + qcount - 1) << 4));
    const int start_f = hi_first[8] & ~3;
    const int n_f     = ((hi_last[13] + 3) - start_f + 3) & ~3;   // <= ~784

    __shared__ float lds[2 * LROW];

    // ---- stage: load union rows once, combine into 2 LDS rows ----
    for (int f = threadIdx.x * 4; f < n_f; f += 64 * 4) {
        float4 a0 = make_float4(0.f, 0.f, 0.f, 0.f);
        float4 a1 = make_float4(0.f, 0.f, 0.f, 0.f);
        #pragma unroll
        for (int j = 0; j < TAPS; ++j) {   // first 6 always present
            const float4 v = *(const float4*)(img + (size_t)rowi[j] * ROW_F + start_f + f);
            a0.x = fmaf(wa[j], v.x, a0.x); a0.y = fmaf(wa[j], v.y, a0.y);
            a0.z = fmaf(wa[j], v.z, a0.z); a0.w = fmaf(wa[j], v.w, a0.w);
            a1.x = fmaf(wb[j], v.x, a1.x); a1.y = fmaf(wb[j], v.y, a1.y);
            a1.z = fmaf(wb[j], v.z, a1.z); a1.w = fmaf(wb[j], v.w, a1.w);
        }
        for (int j = TAPS; j < m; ++j) {   // dynamic tail 0..8 rows
            const float4 v = *(const float4*)(img + (size_t)rowi[j] * ROW_F + start_f + f);
            a1.x = fmaf(wb[j], v.x, a1.x); a1.y = fmaf(wb[j], v.y, a1.y);
            a1.z = fmaf(wb[j], v.z, a1.z); a1.w = fmaf(wb[j], v.w, a1.w);
        }
        *(float4*)(lds + f) = a0;
        *(float4*)(lds + LROW + f) = a1;
    }
    __syncthreads();

    // ---- compute: lanes 0..31 -> p0, lanes 32..63 -> p1 ----
    const int t    = threadIdx.x;
    const int sel  = t >> 5;               // 0 or 1
    const int qi   = t & 31;
    if (qi < qcount) {
        const int q = q0 + qi;
        const float* h  = htab + ((size_t)(box * OUT + q) << 4);
        const int*   hi = (const int*)h;
        const float* l  = lds + sel * LROW;
        float a0 = 0.0f, a1 = 0.0f, a2 = 0.0f;
        #pragma unroll
        for (int k = 0; k < TAPS; ++k) {
            const float w  = h[k];
            const int   li = hi[8 + k] - start_f;
            a0 = fmaf(w, l[li + 0], a0);
            a1 = fmaf(w, l[li + 1], a1);
            a2 = fmaf(w, l[li + 2], a2);
        }
        const size_t o = (((size_t)box * OUT + (p0 + sel)) * OUT + q) * 3;
        out[o + 0] = a0;
        out[o + 1] = a1;
        out[o + 2] = a2;
    }
}

// ---------------- Fallback (round-4 single kernel, no workspace) ----------------
__global__ __launch_bounds__(256) void crop_resize_fallback(
    const float* __restrict__ scores, const float* __restrict__ boxes,
    const float* __restrict__ img, float* __restrict__ out)
{
    const int p = blockIdx.x, box = blockIdx.y;
    const float b0 = boxes[box*4+0], b1 = boxes[box*4+1];
    const float b2 = boxes[box*4+2], b3 = boxes[box*4+3];
    const int y0 = (int)(b0*(float)IMG_H), x0 = (int)(b1*(float)IMG_W);
    const int y1 = (int)(b2*(float)IMG_H), x1 = (int)(b3*(float)IMG_W);
    const int ch = max(y1-y0,1), cw = max(x1-x0,1);
    const bool valid = (scores[0]>=TH)&&(scores[box]>=TH)&&(b1>=0.0f)&&(b3<=1.0f);
    const float vmask = valid?1.0f:0.0f;
    float wh[TAPS]; int ih[TAPS];
    {
        const float src = ((float)p+0.5f)*((float)ch/(float)OUT)-0.5f;
        const int base = (int)floorf(src)-2;
        float s = 0.0f;
        #pragma unroll
        for (int a = 0; a < TAPS; ++a) {
            const float d = src-(float)(base+a);
            const float w = (fabsf(d)<3.0f)?sincf(d)*sincf(d*(1.0f/3.0f)):0.0f;
            wh[a]=w; s+=w;
            int t=base+a; t=t<0?0:t; t=t>ch-1?ch-1:t; ih[a]=t+y0;
        }
        const float inv = 1.0f/s;
        #pragma unroll
        for (int a = 0; a < TAPS; ++a) wh[a]*=inv;
    }
    const int start_f = (x0*3)&~3;
    const int end_f = (x0+cw)*3;
    const int n_f = end_f-start_f;
    __shared__ float lds[6152];
    {
        const float* r0 = img+(size_t)ih[0]*ROW_F+start_f;
        const float* r1 = img+(size_t)ih[1]*ROW_F+start_f;
        const float* r2 = img+(size_t)ih[2]*ROW_F+start_f;
        const float* r3 = img+(size_t)ih[3]*ROW_F+start_f;
        const float* r4 = img+(size_t)ih[4]*ROW_F+start_f;
        const float* r5 = img+(size_t)ih[5]*ROW_F+start_f;
        for (int f = threadIdx.x*4; f < n_f; f += 256*4) {
            const float4 u0=*(const float4*)(r0+f), u1=*(const float4*)(r1+f);
            const float4 u2=*(const float4*)(r2+f), u3=*(const float4*)(r3+f);
            const float4 u4=*(const float4*)(r4+f), u5=*(const float4*)(r5+f);
            float4 acc;
            acc.x=wh[0]*u0.x+wh[1]*u1.x+wh[2]*u2.x+wh[3]*u3.x+wh[4]*u4.x+wh[5]*u5.x;
            acc.y=wh[0]*u0.y+wh[1]*u1.y+wh[2]*u2.y+wh[3]*u3.y+wh[4]*u4.y+wh[5]*u5.y;
            acc.z=wh[0]*u0.z+wh[1]*u1.z+wh[2]*u2.z+wh[3]*u3.z+wh[4]*u4.z+wh[5]*u5.z;
            acc.w=wh[0]*u0.w+wh[1]*u1.w+wh[2]*u2.w+wh[3]*u3.w+wh[4]*u4.w+wh[5]*u5.w;
            *(float4*)(lds+f)=acc;
        }
    }
    __syncthreads();
    const float wscale = (float)cw/(float)OUT;
    for (int q = threadIdx.x; q < OUT; q += 256) {
        const float src = ((float)q+0.5f)*wscale-0.5f;
        const int basew = (int)floorf(src)-2;
        float ww[TAPS]; float s = 0.0f;
        #pragma unroll
        for (int k = 0; k < TAPS; ++k) {
            const float d = src-(float)(basew+k);
            const float w = (fabsf(d)<3.0f)?sincf(d)*sincf(d*(1.0f/3.0f)):0.0f;
            ww[k]=w; s+=w;
        }
        const float inv = 1.0f/s;
        float a0=0,a1=0,a2=0;
        #pragma unroll
        for (int k = 0; k < TAPS; ++k) {
            int t=basew+k; t=t<0?0:t; t=t>cw-1?cw-1:t;
            const int hb=(x0+t)*3-start_f;
            a0=fmaf(ww[k],lds[hb+0],a0);
            a1=fmaf(ww[k],lds[hb+1],a1);
            a2=fmaf(ww[k],lds[hb+2],a2);
        }
        const float mfac = vmask*inv;
        const size_t o = (((size_t)box*OUT+p)*OUT+q)*3;
        out[o+0]=a0*mfac; out[o+1]=a1*mfac; out[o+2]=a2*mfac;
    }
}

extern "C" void kernel_launch(void* const* d_in, const int* in_sizes, int n_in,
                              void* d_out, int out_size, void* d_ws, size_t ws_size,
                              hipStream_t stream) {
    const float* scores = (const float*)d_in[0];   // (100,)
    const float* boxes  = (const float*)d_in[1];   // (100,4)
    const float* img    = (const float*)d_in[2];   // (1,2048,2048,3)
    float* out = (float*)d_out;                    // (10,260,260,3)

    const size_t tab_bytes = (size_t)NB * OUT * 16 * sizeof(float);  // 166,400 B each
    if (ws_size < 2 * tab_bytes) {
        crop_resize_fallback<<<dim3(OUT, NB), dim3(256), 0, stream>>>(scores, boxes, img, out);
        return;
    }
    float* htab = (float*)d_ws;
    float* vtab = (float*)((char*)d_ws + tab_bytes);

    tables_kernel<<<dim3(NB), dim3(320), 0, stream>>>(scores, boxes, htab, vtab);
    crop_resize_pair<<<dim3(SEGS, OUT / 2, NB), dim3(64), 0, stream>>>(img, htab, vtab, out);
}

// Round 7
// 118.455 us; speedup vs baseline: 1.0067x; 1.0067x over previous
//
#include <hip/hip_runtime.h>
#include <math.h>

#define OUT 260
#define TAPS 6
#define IMG_H 2048
#define IMG_W 2048
#define ROW_F (IMG_W * 3)            // 6144 floats per image row
#define NB 10
#define TH 0.8f
#define SEGS 5                       // 5 segs * 52 cols = 260
#define QB 52
#define LDSF 1248                    // floats: worst seg span = 51*7.88+6 ~ 408 px * 3 = 1224 + pad

__device__ __forceinline__ float sincf(float x) {
    if (x == 0.0f) return 1.0f;
    float px = 3.14159265358979323846f * x;
    return __sinf(px) / px;
}

// Record layout per (box, idx), 16 dwords = 64 B:
//   f[0..5]  : normalized weights (vertical table: also * vmask)
//   i[8..13] : horizontal: clamped absolute float index (x0+t)*3
//              vertical:   clamped absolute row index (t+y0)

__global__ __launch_bounds__(320) void tables_kernel(
    const float* __restrict__ scores, const float* __restrict__ boxes,
    float* __restrict__ htab, float* __restrict__ vtab)
{
    const int box = blockIdx.x;
    const float b0 = boxes[box * 4 + 0];
    const float b1 = boxes[box * 4 + 1];
    const float b2 = boxes[box * 4 + 2];
    const float b3 = boxes[box * 4 + 3];

    const int y0 = (int)(b0 * (float)IMG_H);
    const int x0 = (int)(b1 * (float)IMG_W);
    const int y1 = (int)(b2 * (float)IMG_H);
    const int x1 = (int)(b3 * (float)IMG_W);
    const int ch = max(y1 - y0, 1);
    const int cw = max(x1 - x0, 1);

    const bool valid = (scores[0] >= TH) && (scores[box] >= TH)
                    && (b1 >= 0.0f) && (b3 <= 1.0f);
    const float vmask = valid ? 1.0f : 0.0f;

    const int t = threadIdx.x;
    if (t >= OUT) return;

    // ---- horizontal record ----
    {
        const float src = ((float)t + 0.5f) * ((float)cw / (float)OUT) - 0.5f;
        const int base = (int)floorf(src) - 2;
        float w[TAPS]; int id[TAPS];
        float s = 0.0f;
        #pragma unroll
        for (int k = 0; k < TAPS; ++k) {
            const float d = src - (float)(base + k);
            const float wv = (fabsf(d) < 3.0f) ? sincf(d) * sincf(d * (1.0f / 3.0f)) : 0.0f;
            w[k] = wv; s += wv;
            int tt = base + k; tt = tt < 0 ? 0 : tt; tt = tt > cw - 1 ? cw - 1 : tt;
            id[k] = (x0 + tt) * 3;
        }
        const float inv = 1.0f / s;
        float* h = htab + ((size_t)(box * OUT + t) << 4);
        int*   hi = (int*)h;
        #pragma unroll
        for (int k = 0; k < TAPS; ++k) { h[k] = w[k] * inv; hi[8 + k] = id[k]; }
        h[6] = 0.0f; h[7] = 0.0f; hi[14] = 0; hi[15] = 0;
    }

    // ---- vertical record (vmask folded in) ----
    {
        const float src = ((float)t + 0.5f) * ((float)ch / (float)OUT) - 0.5f;
        const int base = (int)floorf(src) - 2;
        float w[TAPS]; int id[TAPS];
        float s = 0.0f;
        #pragma unroll
        for (int k = 0; k < TAPS; ++k) {
            const float d = src - (float)(base + k);
            const float wv = (fabsf(d) < 3.0f) ? sincf(d) * sincf(d * (1.0f / 3.0f)) : 0.0f;
            w[k] = wv; s += wv;
            int tt = base + k; tt = tt < 0 ? 0 : tt; tt = tt > ch - 1 ? ch - 1 : tt;
            id[k] = tt + y0;
        }
        const float inv = vmask / s;
        float* v = vtab + ((size_t)(box * OUT + t) << 4);
        int*   vi = (int*)v;
        #pragma unroll
        for (int k = 0; k < TAPS; ++k) { v[k] = w[k] * inv; vi[8 + k] = id[k]; }
        v[6] = 0.0f; v[7] = 0.0f; vi[14] = 0; vi[15] = 0;
    }
}

__global__ __launch_bounds__(64) void crop_resize_seg(
    const float* __restrict__ img,
    const float* __restrict__ htab,
    const float* __restrict__ vtab,
    float* __restrict__ out)
{
    const int seg = blockIdx.x;      // 0..4
    const int p   = blockIdx.y;      // 0..259
    const int box = blockIdx.z;      // 0..9
    const int q0  = seg * QB;

    // ---- vertical record (block-uniform) ----
    const float* vrec = vtab + ((size_t)(box * OUT + p) << 4);
    const int*   vi   = (const int*)vrec;
    float wh[TAPS]; int rows[TAPS];
    #pragma unroll
    for (int k = 0; k < TAPS; ++k) { wh[k] = vrec[k]; rows[k] = vi[8 + k]; }

    // ---- per-thread horizontal record: prefetch BEFORE the barrier ----
    const int q  = q0 + (int)threadIdx.x;          // threadIdx.x < 52 are active
    const bool qact = (threadIdx.x < QB);
    float4 hw01, hw23;        // weights 0..3
    float  hw4, hw5;
    int    li0 = 0, li1 = 0, li2 = 0, li3 = 0, li4 = 0, li5 = 0;
    if (qact) {
        const float* h = htab + ((size_t)(box * OUT + q) << 4);
        const int*  hi = (const int*)h;
        hw01 = *(const float4*)(h);
        hw23 = *(const float4*)(h + 4);   // [w4, w5, pad, pad]
        hw4 = hw23.x; hw5 = hw23.y;
        li0 = hi[8]; li1 = hi[9]; li2 = hi[10];
        li3 = hi[11]; li4 = hi[12]; li5 = hi[13];
    }

    // ---- staged span from first/last q's tap indices ----
    const int* hi_first = (const int*)(htab + ((size_t)(box * OUT + q0) << 4));
    const int* hi_last  = (const int*)(htab + ((size_t)(box * OUT + q0 + QB - 1) << 4));
    const int start_f = hi_first[8] & ~3;
    const int n_f     = ((hi_last[13] + 3) - start_f + 3) & ~3;

    __shared__ float lds[LDSF];

    // ---- stage: 6 rows, vertical combine in regs, 1 fp32 LDS row ----
    {
        const float* r0 = img + (size_t)rows[0] * ROW_F + start_f;
        const float* r1 = img + (size_t)rows[1] * ROW_F + start_f;
        const float* r2 = img + (size_t)rows[2] * ROW_F + start_f;
        const float* r3 = img + (size_t)rows[3] * ROW_F + start_f;
        const float* r4 = img + (size_t)rows[4] * ROW_F + start_f;
        const float* r5 = img + (size_t)rows[5] * ROW_F + start_f;

        for (int f = threadIdx.x * 4; f < n_f; f += 64 * 4) {
            const float4 v0 = *(const float4*)(r0 + f);
            const float4 v1 = *(const float4*)(r1 + f);
            const float4 v2 = *(const float4*)(r2 + f);
            const float4 v3 = *(const float4*)(r3 + f);
            const float4 v4 = *(const float4*)(r4 + f);
            const float4 v5 = *(const float4*)(r5 + f);
            float4 acc;
            acc.x = wh[0]*v0.x + wh[1]*v1.x + wh[2]*v2.x + wh[3]*v3.x + wh[4]*v4.x + wh[5]*v5.x;
            acc.y = wh[0]*v0.y + wh[1]*v1.y + wh[2]*v2.y + wh[3]*v3.y + wh[4]*v4.y + wh[5]*v5.y;
            acc.z = wh[0]*v0.z + wh[1]*v1.z + wh[2]*v2.z + wh[3]*v3.z + wh[4]*v4.z + wh[5]*v5.z;
            acc.w = wh[0]*v0.w + wh[1]*v1.w + wh[2]*v2.w + wh[3]*v3.w + wh[4]*v4.w + wh[5]*v5.w;
            *(float4*)(lds + f) = acc;
        }
    }
    __syncthreads();

    // ---- compute: single pass, lanes 0..51 active ----
    if (qact) {
        float a0 = 0.0f, a1 = 0.0f, a2 = 0.0f;
        {
            const int i0 = li0 - start_f;
            a0 = fmaf(hw01.x, lds[i0 + 0], a0);
            a1 = fmaf(hw01.x, lds[i0 + 1], a1);
            a2 = fmaf(hw01.x, lds[i0 + 2], a2);
        }
        {
            const int i1 = li1 - start_f;
            a0 = fmaf(hw01.y, lds[i1 + 0], a0);
            a1 = fmaf(hw01.y, lds[i1 + 1], a1);
            a2 = fmaf(hw01.y, lds[i1 + 2], a2);
        }
        {
            const int i2 = li2 - start_f;
            a0 = fmaf(hw01.z, lds[i2 + 0], a0);
            a1 = fmaf(hw01.z, lds[i2 + 1], a1);
            a2 = fmaf(hw01.z, lds[i2 + 2], a2);
        }
        {
            const int i3 = li3 - start_f;
            a0 = fmaf(hw01.w, lds[i3 + 0], a0);
            a1 = fmaf(hw01.w, lds[i3 + 1], a1);
            a2 = fmaf(hw01.w, lds[i3 + 2], a2);
        }
        {
            const int i4 = li4 - start_f;
            a0 = fmaf(hw4, lds[i4 + 0], a0);
            a1 = fmaf(hw4, lds[i4 + 1], a1);
            a2 = fmaf(hw4, lds[i4 + 2], a2);
        }
        {
            const int i5 = li5 - start_f;
            a0 = fmaf(hw5, lds[i5 + 0], a0);
            a1 = fmaf(hw5, lds[i5 + 1], a1);
            a2 = fmaf(hw5, lds[i5 + 2], a2);
        }
        const size_t o = (((size_t)box * OUT + p) * OUT + q) * 3;
        out[o + 0] = a0;
        out[o + 1] = a1;
        out[o + 2] = a2;
    }
}

// ---------------- Fallback (round-4 single kernel, no workspace) ----------------
__global__ __launch_bounds__(256) void crop_resize_fallback(
    const float* __restrict__ scores, const float* __restrict__ boxes,
    const float* __restrict__ img, float* __restrict__ out)
{
    const int p = blockIdx.x, box = blockIdx.y;
    const float b0 = boxes[box*4+0], b1 = boxes[box*4+1];
    const float b2 = boxes[box*4+2], b3 = boxes[box*4+3];
    const int y0 = (int)(b0*(float)IMG_H), x0 = (int)(b1*(float)IMG_W);
    const int y1 = (int)(b2*(float)IMG_H), x1 = (int)(b3*(float)IMG_W);
    const int ch = max(y1-y0,1), cw = max(x1-x0,1);
    const bool valid = (scores[0]>=TH)&&(scores[box]>=TH)&&(b1>=0.0f)&&(b3<=1.0f);
    const float vmask = valid?1.0f:0.0f;
    float wh[TAPS]; int ih[TAPS];
    {
        const float src = ((float)p+0.5f)*((float)ch/(float)OUT)-0.5f;
        const int base = (int)floorf(src)-2;
        float s = 0.0f;
        #pragma unroll
        for (int a = 0; a < TAPS; ++a) {
            const float d = src-(float)(base+a);
            const float w = (fabsf(d)<3.0f)?sincf(d)*sincf(d*(1.0f/3.0f)):0.0f;
            wh[a]=w; s+=w;
            int t=base+a; t=t<0?0:t; t=t>ch-1?ch-1:t; ih[a]=t+y0;
        }
        const float inv = 1.0f/s;
        #pragma unroll
        for (int a = 0; a < TAPS; ++a) wh[a]*=inv;
    }
    const int start_f = (x0*3)&~3;
    const int end_f = (x0+cw)*3;
    const int n_f = end_f-start_f;
    __shared__ float lds[6152];
    {
        const float* r0 = img+(size_t)ih[0]*ROW_F+start_f;
        const float* r1 = img+(size_t)ih[1]*ROW_F+start_f;
        const float* r2 = img+(size_t)ih[2]*ROW_F+start_f;
        const float* r3 = img+(size_t)ih[3]*ROW_F+start_f;
        const float* r4 = img+(size_t)ih[4]*ROW_F+start_f;
        const float* r5 = img+(size_t)ih[5]*ROW_F+start_f;
        for (int f = threadIdx.x*4; f < n_f; f += 256*4) {
            const float4 u0=*(const float4*)(r0+f), u1=*(const float4*)(r1+f);
            const float4 u2=*(const float4*)(r2+f), u3=*(const float4*)(r3+f);
            const float4 u4=*(const float4*)(r4+f), u5=*(const float4*)(r5+f);
            float4 acc;
            acc.x=wh[0]*u0.x+wh[1]*u1.x+wh[2]*u2.x+wh[3]*u3.x+wh[4]*u4.x+wh[5]*u5.x;
            acc.y=wh[0]*u0.y+wh[1]*u1.y+wh[2]*u2.y+wh[3]*u3.y+wh[4]*u4.y+wh[5]*u5.y;
            acc.z=wh[0]*u0.z+wh[1]*u1.z+wh[2]*u2.z+wh[3]*u3.z+wh[4]*u4.z+wh[5]*u5.z;
            acc.w=wh[0]*u0.w+wh[1]*u1.w+wh[2]*u2.w+wh[3]*u3.w+wh[4]*u4.w+wh[5]*u5.w;
            *(float4*)(lds+f)=acc;
        }
    }
    __syncthreads();
    const float wscale = (float)cw/(float)OUT;
    for (int q = threadIdx.x; q < OUT; q += 256) {
        const float src = ((float)q+0.5f)*wscale-0.5f;
        const int basew = (int)floorf(src)-2;
        float ww[TAPS]; float s = 0.0f;
        #pragma unroll
        for (int k = 0; k < TAPS; ++k) {
            const float d = src-(float)(basew+k);
            const float w = (fabsf(d)<3.0f)?sincf(d)*sincf(d*(1.0f/3.0f)):0.0f;
            ww[k]=w; s+=w;
        }
        const float inv = 1.0f/s;
        float a0=0,a1=0,a2=0;
        #pragma unroll
        for (int k = 0; k < TAPS; ++k) {
            int t=basew+k; t=t<0?0:t; t=t>cw-1?cw-1:t;
            const int hb=(x0+t)*3-start_f;
            a0=fmaf(ww[k],lds[hb+0],a0);
            a1=fmaf(ww[k],lds[hb+1],a1);
            a2=fmaf(ww[k],lds[hb+2],a2);
        }
        const float mfac = vmask*inv;
        const size_t o = (((size_t)box*OUT+p)*OUT+q)*3;
        out[o+0]=a0*mfac; out[o+1]=a1*mfac; out[o+2]=a2*mfac;
    }
}

extern "C" void kernel_launch(void* const* d_in, const int* in_sizes, int n_in,
                              void* d_out, int out_size, void* d_ws, size_t ws_size,
                              hipStream_t stream) {
    const float* scores = (const float*)d_in[0];   // (100,)
    const float* boxes  = (const float*)d_in[1];   // (100,4)
    const float* img    = (const float*)d_in[2];   // (1,2048,2048,3)
    float* out = (float*)d_out;                    // (10,260,260,3)

    const size_t tab_bytes = (size_t)NB * OUT * 16 * sizeof(float);  // 166,400 B each
    if (ws_size < 2 * tab_bytes) {
        crop_resize_fallback<<<dim3(OUT, NB), dim3(256), 0, stream>>>(scores, boxes, img, out);
        return;
    }
    float* htab = (float*)d_ws;
    float* vtab = (float*)((char*)d_ws + tab_bytes);

    tables_kernel<<<dim3(NB), dim3(320), 0, stream>>>(scores, boxes, htab, vtab);
    crop_resize_seg<<<dim3(SEGS, OUT, NB), dim3(64), 0, stream>>>(img, htab, vtab, out);
}